// Round 1
// baseline (643.625 us; speedup 1.0000x reference)
//
#include <hip/hip_runtime.h>

typedef unsigned short u16;
typedef unsigned int u32;
typedef __bf16 bf16x8 __attribute__((ext_vector_type(8)));
typedef float f32x4 __attribute__((ext_vector_type(4)));

#define NN 2048      // nodes
#define NE 6144      // edges
#define DVIN 128
#define DVOUT 64
#define DEIN 16
#define DEOUT 16

__device__ __forceinline__ u16 f2b(float f) {
  __bf16 b = (__bf16)f;
  return __builtin_bit_cast(u16, b);
}

__device__ __forceinline__ void async16(const void* g, void* l) {
  __builtin_amdgcn_global_load_lds(
      (const __attribute__((address_space(1))) void*)g,
      (__attribute__((address_space(3))) void*)l, 16, 0, 0);
}

__device__ __forceinline__ bf16x8 load8(const u16* p) {
  union { uint4 u; bf16x8 b; } w;
  w.u = *(const uint4*)p;
  return w.b;
}

// ---------------- small kernels ----------------

// d_e[j] = dot(H_e[j,:16], p_v)
__global__ __launch_bounds__(256) void k_de(const float* __restrict__ He,
                                            const float* __restrict__ pv,
                                            float* __restrict__ de) {
  int j = blockIdx.x * 256 + threadIdx.x;
  float s = 0.f;
#pragma unroll
  for (int k = 0; k < DEIN; k++) s += He[j * DEIN + k] * pv[k];
  de[j] = s;
}

// Tb = bf16(T); Tbs = bf16(T * d_e[col])   (row-major [NN,NE])
__global__ __launch_bounds__(256) void k_tb(const float* __restrict__ T,
                                            const float* __restrict__ de,
                                            u16* __restrict__ Tb,
                                            u16* __restrict__ Tbs) {
  size_t idx = (size_t)blockIdx.x * 256 + threadIdx.x;
  size_t f = idx * 8;
  float4 v0 = *(const float4*)(T + f);
  float4 v1 = *(const float4*)(T + f + 4);
  int col = (int)(f % (size_t)NE);
  float4 d0 = *(const float4*)(de + col);
  float4 d1 = *(const float4*)(de + col + 4);
  float v[8] = {v0.x, v0.y, v0.z, v0.w, v1.x, v1.y, v1.z, v1.w};
  float d[8] = {d0.x, d0.y, d0.z, d0.w, d1.x, d1.y, d1.z, d1.w};
  union { u16 s[8]; uint4 u; } a, b;
#pragma unroll
  for (int j = 0; j < 8; j++) { a.s[j] = f2b(v[j]); b.s[j] = f2b(v[j] * d[j]); }
  *(uint4*)(Tb + f) = a.u;
  *(uint4*)(Tbs + f) = b.u;
}

// Xt[d][i] = bf16( (H_v @ W_v)[i][d] )   (transposed, B-operand friendly)
__global__ __launch_bounds__(256) void k_x(const float* __restrict__ Hv,
                                           const float* __restrict__ Wv,
                                           u16* __restrict__ Xt) {
  int i = blockIdx.x * 256 + threadIdx.x;
  int d = blockIdx.y;
  float s = 0.f;
#pragma unroll 8
  for (int k = 0; k < DVIN; k++) s += Hv[i * DVIN + k] * Wv[k * DVOUT + d];
  Xt[(size_t)d * NN + i] = f2b(s);
}

// d_v[i] = dot(Hv_out[i,:64], p_e)
__global__ __launch_bounds__(256) void k_dv(const float* __restrict__ HvOut,
                                            const float* __restrict__ pe,
                                            float* __restrict__ dv) {
  int i = blockIdx.x * 256 + threadIdx.x;
  float s = 0.f;
#pragma unroll
  for (int c = 0; c < DVOUT; c++) s += HvOut[i * DVOUT + c] * pe[c];
  dv[i] = s;
}

// transpose T [NN,NE] fp32 -> Tt [NE,NN] bf16, Tts = Tt * d_v[col]
__global__ __launch_bounds__(256) void k_tt(const float* __restrict__ T,
                                            const float* __restrict__ dv,
                                            u16* __restrict__ Tt,
                                            u16* __restrict__ Tts) {
  __shared__ float tile[32][33];
  int tx = threadIdx.x, ty = threadIdx.y;
  int bx = blockIdx.x, by = blockIdx.y;  // bx: E tiles, by: N tiles
  int col = bx * 32 + tx;
#pragma unroll
  for (int r = 0; r < 4; r++) {
    int row = by * 32 + ty + r * 8;
    tile[ty + r * 8][tx] = T[(size_t)row * NE + col];
  }
  __syncthreads();
  int ocol = by * 32 + tx;  // N index (original row)
  float dvv = dv[ocol];
#pragma unroll
  for (int r = 0; r < 4; r++) {
    int orow = bx * 32 + ty + r * 8;  // E index
    float v = tile[tx][ty + r * 8];
    Tt[(size_t)orow * NN + ocol] = f2b(v);
    Tts[(size_t)orow * NN + ocol] = f2b(v * dvv);
  }
}

// Ztb[d][b] = bf16( (H_e @ W_e)[b][d] / (colmax[b] + 1e-10) )
__global__ __launch_bounds__(256) void k_zt(const float* __restrict__ He,
                                            const float* __restrict__ We,
                                            const u32* __restrict__ colmax,
                                            u16* __restrict__ Ztb) {
  int b = blockIdx.x * 256 + threadIdx.x;
  float h[16];
  const float4* hp = (const float4*)(He + (size_t)b * DEIN);
#pragma unroll
  for (int q = 0; q < 4; q++) {
    float4 t = hp[q];
    h[q * 4 + 0] = t.x; h[q * 4 + 1] = t.y; h[q * 4 + 2] = t.z; h[q * 4 + 3] = t.w;
  }
  float inv = 1.0f / (__uint_as_float(colmax[b]) + 1e-10f);
#pragma unroll
  for (int d = 0; d < DEOUT; d++) {
    float s = 0.f;
#pragma unroll
    for (int k = 0; k < DEIN; k++) s += h[k] * We[k * DEOUT + d];
    Ztb[(size_t)d * NE + b] = f2b(s * inv);
  }
}

// ---------------- big GEMM: C = A @ B^T, A[M,K], B[N,K] bf16 ----------------
// EPI 1: node layer  -> Cbf = (diag?1:c)*adj_v, bf16
// EPI 2: edge layer  -> Cbf = (diag?1:c)*adj_e, bf16 + column max (atomicMax)
#define BM 128
#define BN 128
#define BK 64

template <int EPI>
__global__ __launch_bounds__(256) void gemm_bt(const u16* __restrict__ A,
                                               const u16* __restrict__ B,
                                               const float* __restrict__ adj,
                                               u16* __restrict__ C,
                                               u32* __restrict__ colmax,
                                               int M, int N, int K) {
  __shared__ u16 As[BM * BK];
  __shared__ u16 Bs[BN * BK];
  __shared__ u32 cmaxLds[BN];

  const int t = threadIdx.x;
  const int bm0 = blockIdx.y * BM, bn0 = blockIdx.x * BN;
  const int wave = t >> 6, lane = t & 63;
  const int lr = lane & 15, kg = lane >> 4;
  const int wm = (wave >> 1) * 64, wn = (wave & 1) * 64;

  if (EPI == 2 && t < BN) cmaxLds[t] = 0u;

  f32x4 acc[4][4];
#pragma unroll
  for (int i = 0; i < 4; i++)
#pragma unroll
    for (int j = 0; j < 4; j++) acc[i][j] = (f32x4){0.f, 0.f, 0.f, 0.f};

  // staging: thread t loads 8 bf16 (16B). LDS dest stays lane-contiguous
  // (t*16B); the XOR chunk swizzle is applied on the GLOBAL side so the
  // ds_read_b128 fragment loads land 2-way per bank (free, m136).
  const int arow = t >> 3;                         // 0..31
  const int acolsw = (((t & 7) ^ (arow & 7)) * 8); // swizzled global col
  const u16* Ag = A + (size_t)(bm0 + arow) * K + acolsw;
  const u16* Bg = B + (size_t)(bn0 + arow) * K + acolsw;
  u16* Al = &As[t * 8];
  u16* Bl = &Bs[t * 8];

  for (int k0 = 0; k0 < K; k0 += BK) {
    __syncthreads();
#pragma unroll
    for (int r = 0; r < 4; r++) {
      async16(Ag + (size_t)(r * 32) * K + k0, Al + r * 32 * BK);
      async16(Bg + (size_t)(r * 32) * K + k0, Bl + r * 32 * BK);
    }
    __syncthreads();
#pragma unroll
    for (int kk = 0; kk < BK; kk += 32) {
      bf16x8 af[4], bf[4];
#pragma unroll
      for (int mi = 0; mi < 4; mi++) {
        int row = wm + mi * 16 + lr;
        int c = (kk >> 3) + kg;
        af[mi] = load8(&As[row * BK + ((c ^ (row & 7)) << 3)]);
      }
#pragma unroll
      for (int ni = 0; ni < 4; ni++) {
        int row = wn + ni * 16 + lr;
        int c = (kk >> 3) + kg;
        bf[ni] = load8(&Bs[row * BK + ((c ^ (row & 7)) << 3)]);
      }
#pragma unroll
      for (int mi = 0; mi < 4; mi++)
#pragma unroll
        for (int ni = 0; ni < 4; ni++)
          acc[mi][ni] = __builtin_amdgcn_mfma_f32_16x16x32_bf16(
              af[mi], bf[ni], acc[mi][ni], 0, 0, 0);
    }
  }

  // epilogue: C layout col=lane&15, row=(lane>>4)*4+reg  (m89/m91 verified)
#pragma unroll
  for (int ni = 0; ni < 4; ni++) {
    const int cj = bn0 + wn + ni * 16 + lr;
    float cm = 0.f;
#pragma unroll
    for (int mi = 0; mi < 4; mi++) {
#pragma unroll
      for (int r = 0; r < 4; r++) {
        const int ci = bm0 + wm + mi * 16 + kg * 4 + r;
        float v = acc[mi][ni][r];
        if (ci == cj) v = 1.0f;
        v *= adj[(size_t)ci * N + cj];
        C[(size_t)ci * N + cj] = f2b(v);
        if (EPI == 2) cm = fmaxf(cm, v);
      }
    }
    if (EPI == 2)
      atomicMax(&cmaxLds[wn + ni * 16 + lr], __float_as_uint(cm));
  }
  if (EPI == 2) {
    __syncthreads();
    if (t < BN) atomicMax(&colmax[bn0 + t], cmaxLds[t]);
  }
}

// ---------------- thin MFMA gemms (N<=64), K split over 4 waves ----------------

// Hv_out = A1 @ X + b_v ;  A1 [NN,NN] bf16, Xt [64][NN] bf16 (B^T layout)
__global__ __launch_bounds__(256) void k_hv(const u16* __restrict__ A1,
                                            const u16* __restrict__ Xt,
                                            const float* __restrict__ bv,
                                            float* __restrict__ out) {
  __shared__ float red[4 * 1024];
  const int t = threadIdx.x, wave = t >> 6, lane = t & 63;
  const int lr = lane & 15, kg = lane >> 4;
  const int m0 = blockIdx.x * 16;
  const int K = NN;
  f32x4 acc[4];
#pragma unroll
  for (int i = 0; i < 4; i++) acc[i] = (f32x4){0.f, 0.f, 0.f, 0.f};
  const int kbeg = wave * (K / 4), kend = kbeg + (K / 4);
  for (int k = kbeg; k < kend; k += 32) {
    bf16x8 af = load8(&A1[(size_t)(m0 + lr) * K + k + kg * 8]);
#pragma unroll
    for (int ni = 0; ni < 4; ni++) {
      bf16x8 bfr = load8(&Xt[(size_t)(ni * 16 + lr) * K + k + kg * 8]);
      acc[ni] = __builtin_amdgcn_mfma_f32_16x16x32_bf16(af, bfr, acc[ni], 0, 0, 0);
    }
  }
#pragma unroll
  for (int ni = 0; ni < 4; ni++)
#pragma unroll
    for (int r = 0; r < 4; r++)
      red[wave * 1024 + (kg * 4 + r) * 64 + ni * 16 + lr] = acc[ni][r];
  __syncthreads();
#pragma unroll
  for (int q = 0; q < 4; q++) {
    int e = t + 256 * q;
    int row = e >> 6, col = e & 63;
    float v = red[e] + red[1024 + e] + red[2048 + e] + red[3072 + e] + bv[col];
    out[(size_t)(m0 + row) * DVOUT + col] = v;
  }
}

// He_out = adjE @ Z + b_e ; adjE [NE,NE] bf16, Ztb [16][NE] bf16
__global__ __launch_bounds__(256) void k_he(const u16* __restrict__ adjE,
                                            const u16* __restrict__ Ztb,
                                            const float* __restrict__ be,
                                            float* __restrict__ out) {
  __shared__ float red[4 * 256];
  const int t = threadIdx.x, wave = t >> 6, lane = t & 63;
  const int lr = lane & 15, kg = lane >> 4;
  const int m0 = blockIdx.x * 16;
  const int K = NE;
  f32x4 acc = (f32x4){0.f, 0.f, 0.f, 0.f};
  const int kbeg = wave * (K / 4), kend = kbeg + (K / 4);
  for (int k = kbeg; k < kend; k += 32) {
    bf16x8 af = load8(&adjE[(size_t)(m0 + lr) * K + k + kg * 8]);
    bf16x8 bfr = load8(&Ztb[(size_t)lr * K + k + kg * 8]);
    acc = __builtin_amdgcn_mfma_f32_16x16x32_bf16(af, bfr, acc, 0, 0, 0);
  }
#pragma unroll
  for (int r = 0; r < 4; r++)
    red[wave * 256 + (kg * 4 + r) * 16 + lr] = acc[r];
  __syncthreads();
  {
    int row = t >> 4, col = t & 15;
    float v = red[t] + red[256 + t] + red[512 + t] + red[768 + t] + be[col];
    out[(size_t)(m0 + row) * DEOUT + col] = v;
  }
}

// ---------------- launcher ----------------
extern "C" void kernel_launch(void* const* d_in, const int* in_sizes, int n_in,
                              void* d_out, int out_size, void* d_ws, size_t ws_size,
                              hipStream_t stream) {
  const float* H_v = (const float*)d_in[0];
  const float* H_e = (const float*)d_in[1];
  const float* adj_v = (const float*)d_in[2];
  const float* adj_e = (const float*)d_in[3];
  const float* T = (const float*)d_in[4];
  const float* W_v = (const float*)d_in[5];
  const float* b_v = (const float*)d_in[6];
  const float* p_v = (const float*)d_in[7];
  const float* W_e = (const float*)d_in[8];
  const float* b_e = (const float*)d_in[9];
  const float* p_e = (const float*)d_in[10];
  float* outHv = (float*)d_out;              // [2048,64]
  float* outHe = (float*)d_out + NN * DVOUT; // [6144,16]

  char* ws = (char*)d_ws;
  u16* Tb   = (u16*)(ws + 0);           // 25165824
  u16* Tbs  = (u16*)(ws + 25165824);    // 25165824
  u16* Tt   = (u16*)(ws + 50331648);    // 25165824
  u16* Tts  = (u16*)(ws + 75497472);    // 25165824
  u16* adjE = (u16*)(ws + 100663296);   // 75497472
  u16* A1   = (u16*)(ws + 176160768);   // 8388608
  u16* Xt   = (u16*)(ws + 184549376);   // 262144
  u16* Ztb  = (u16*)(ws + 184811520);   // 196608
  float* de = (float*)(ws + 185008128); // 24576
  float* dv = (float*)(ws + 185032704); // 8192
  u32* cmax = (u32*)(ws + 185040896);   // 24576
  // total: 185065472 bytes (~176.5 MiB)

  k_de<<<NE / 256, 256, 0, stream>>>(H_e, p_v, de);
  k_tb<<<(NN * (size_t)NE) / 8 / 256, 256, 0, stream>>>(T, de, Tb, Tbs);
  k_x<<<dim3(NN / 256, DVOUT), 256, 0, stream>>>(H_v, W_v, Xt);
  gemm_bt<1><<<dim3(NN / BN, NN / BM), 256, 0, stream>>>(
      Tbs, Tb, adj_v, A1, nullptr, NN, NN, NE);
  k_hv<<<NN / 16, 256, 0, stream>>>(A1, Xt, b_v, outHv);
  k_dv<<<NN / 256, 256, 0, stream>>>(outHv, p_e, dv);
  k_tt<<<dim3(NE / 32, NN / 32), dim3(32, 8), 0, stream>>>(T, dv, Tt, Tts);
  hipMemsetAsync(cmax, 0, NE * sizeof(u32), stream);
  gemm_bt<2><<<dim3(NE / BN, NE / BM), 256, 0, stream>>>(
      Tts, Tt, adj_e, adjE, cmax, NE, NE, NN);
  k_zt<<<NE / 256, 256, 0, stream>>>(H_e, W_e, cmax, Ztb);
  k_he<<<NE / 16, 256, 0, stream>>>(adjE, Ztb, b_e, outHe);
}